// Round 7
// baseline (276.008 us; speedup 1.0000x reference)
//
#include <hip/hip_runtime.h>
#include <math.h>

// EWRLS level filter. Recurrence collapses to a pure decay scan:
//   S_t = lam*S_{t-1} + x_t,  Q_t = lam*Q_{t-1} + 1,  y_t = S_t / Q_t
//
// R9 -> R10: every ~100us variant (R0 two-kernel, R6, R8, R9) shares one
// structure: a read-only phase then a write+cache-reread phase, globally
// phase-aligned because all blocks are co-resident and progress in
// lockstep -> HBM reads and writes NEVER overlap, and 134 MB of re-read
// rides the L3 path. R10:
//  1. LDS-stage each 32-row chunk (64 KiB): aggregate AND scan read LDS.
//     x is read from the memory system exactly once; no phase-B re-read.
//  2. Rolling grid: 2048 blocks x 256 thr; 64 KiB LDS caps residency at
//     2 blocks/CU = 512 resident -> 4 generations. Gen g's staging reads
//     overlap gen g-1's y writes -> R/W interleave at HBM.
//  3. Flat lookback depth <= 31, batched 4 predecessors per wait (~4-8
//     serial L2/L3 round trips per block, hidden by co-resident block).
// Fence-free carry publish: (flag<<32 | float_bits) in one 64-bit relaxed
// agent-scope atom. Deadlock-free under rolling: ticket order = start
// order; publish precedes lookback (wait-free path); induction from
// ticket 0 => all publishes complete regardless of residency.

namespace {
constexpr int kB = 64;
constexpr int kT = 1024;
constexpr int kC = 512;
constexpr int kRows = 32;              // T-steps per chunk
constexpr int kNJ = kT / kRows;        // 32 chunks along T
constexpr int kCV = kC / 4;            // 128 float4 lanes per row
constexpr int kChunks = kB * kNJ;      // 2048 == grid size
// ws layout (bytes):
//   [0]      uint ticket counter
//   [1024]   u64 carry[kChunks][kCV][4]   (8 MiB) packed (flag<<32 | bits)
constexpr size_t kCarryOffB = 1024;
constexpr size_t kCarryU64 = (size_t)kChunks * kCV * 4;  // 1048576
}

typedef float vfloat4 __attribute__((ext_vector_type(4)));

__device__ __forceinline__ void load_lam(const float* __restrict__ zl, int c0,
                                         float lam[4]) {
  vfloat4 z = *reinterpret_cast<const vfloat4*>(zl + c0);
#pragma unroll
  for (int k = 0; k < 4; ++k) {
    float s = 1.0f / (1.0f + expf(-z[k]));
    lam[k] = fminf(fmaxf(s, 1e-4f), 1.0f - 1e-4f);
  }
}

__device__ __forceinline__ unsigned long long ld_carry(
    const unsigned long long* __restrict__ p) {
  return __hip_atomic_load(p, __ATOMIC_RELAXED, __HIP_MEMORY_SCOPE_AGENT);
}

// Zero ticket + packed-carry words (workspace is poisoned between
// iterations and poison may have flag bits set, so this must run).
extern "C" __global__ __launch_bounds__(256) void ewrls_init(
    unsigned long long* __restrict__ cw, unsigned* __restrict__ tk) {
  size_t i = (size_t)blockIdx.x * 256 + threadIdx.x;
  if (i < kCarryU64) cw[i] = 0ull;
  if (i == 0) *tk = 0u;
}

// One block per chunk c = j*kB + b (j-major: predecessors of (j,b) have
// strictly smaller chunk ids, hence strictly smaller tickets).
extern "C" __global__ __launch_bounds__(256) void ewrls_fused(
    const float* __restrict__ x, const float* __restrict__ zl,
    unsigned* __restrict__ ws, float* __restrict__ y) {
  __shared__ unsigned sh_t;
  __shared__ vfloat4 lds_x[kRows * kCV];    // 64 KiB chunk stage
  if (threadIdx.x == 0)
    sh_t = __hip_atomic_fetch_add(ws, 1u, __ATOMIC_RELAXED,
                                  __HIP_MEMORY_SCOPE_AGENT);
  __syncthreads();
  const int c = (int)sh_t;
  const int j = c >> 6;                  // chunk along T  (c / kB)
  const int b = c & 63;                  // batch row      (c % kB)
  const int cv = (int)(threadIdx.x & 127);
  const int h = (int)(threadIdx.x >> 7); // T-half 0/1 (wave-uniform)

  unsigned long long* __restrict__ carry =
      reinterpret_cast<unsigned long long*>(
          reinterpret_cast<char*>(ws) + kCarryOffB);

  float lam[4];
  load_lam(zl, cv * 4, lam);

  // Stage the whole chunk into LDS (linear; wave = 1 KiB contiguous per
  // instruction). x is read from HBM exactly ONCE in this kernel.
  const size_t cbase = ((size_t)b * kT + (size_t)j * kRows) * kCV;
  const vfloat4* xp = reinterpret_cast<const vfloat4*>(x) + cbase;
#pragma unroll 8
  for (int it = 0; it < 16; ++it) {
    const int o = it * 256 + (int)threadIdx.x;
    lds_x[o] = xp[o];
  }
  __syncthreads();

  // Local decayed aggregate over all 32 rows (snapshot after row 15 for
  // the h=1 seed). Every thread computes the full fold (2x-redundant LDS
  // reads, but LDS BW is not the constraint).
  float A0 = 0.f, A1 = 0.f, A2 = 0.f, A3 = 0.f;
#pragma unroll 8
  for (int t = 0; t < 16; ++t) {
    vfloat4 v = lds_x[t * kCV + cv];
    A0 = fmaf(lam[0], A0, v.x);
    A1 = fmaf(lam[1], A1, v.y);
    A2 = fmaf(lam[2], A2, v.z);
    A3 = fmaf(lam[3], A3, v.w);
  }
  const float L0 = A0, L1 = A1, L2 = A2, L3 = A3;   // rows 0..15 fold
#pragma unroll 8
  for (int t = 16; t < kRows; ++t) {
    vfloat4 v = lds_x[t * kCV + cv];
    A0 = fmaf(lam[0], A0, v.x);
    A1 = fmaf(lam[1], A1, v.y);
    A2 = fmaf(lam[2], A2, v.z);
    A3 = fmaf(lam[3], A3, v.w);
  }

  // Publish packed (flag|bits): wait-free, BEFORE any poll.
  if (h == 0) {
    unsigned long long* cp = carry + (((size_t)c * kCV + cv) << 2);
    union { float f; unsigned u; } q;
    q.f = A0;
    __hip_atomic_store(cp + 0, (1ull << 32) | q.u, __ATOMIC_RELAXED,
                       __HIP_MEMORY_SCOPE_AGENT);
    q.f = A1;
    __hip_atomic_store(cp + 1, (1ull << 32) | q.u, __ATOMIC_RELAXED,
                       __HIP_MEMORY_SCOPE_AGENT);
    q.f = A2;
    __hip_atomic_store(cp + 2, (1ull << 32) | q.u, __ATOMIC_RELAXED,
                       __HIP_MEMORY_SCOPE_AGENT);
    q.f = A3;
    __hip_atomic_store(cp + 3, (1ull << 32) | q.u, __ATOMIC_RELAXED,
                       __HIP_MEMORY_SCOPE_AGENT);
  }

  // lam^16 and lam^32.
  float l16[4], l32[4];
#pragma unroll
  for (int k = 0; k < 4; ++k) {
    float p = lam[k];
    p = p * p; p = p * p; p = p * p; p = p * p;
    l16[k] = p;
    l32[k] = p * p;
  }

  // Lookback (depth <= 31): batches of 4 predecessors -> issue 16 u64
  // loads, then test+fold in ascending order (verified fold). All static
  // indices (full unroll) so u[][] stays in registers.
  float G0 = 0.f, G1 = 0.f, G2 = 0.f, G3 = 0.f;
  float p0 = 1.f, p1 = 1.f, p2 = 1.f, p3 = 1.f;
  for (int i0 = 0; i0 < j; i0 += 4) {
    const int n = j - i0;
    unsigned long long u[4][4];
#pragma unroll
    for (int k = 0; k < 4; ++k) {
      if (k < n) {
        const unsigned long long* cp =
            carry + ((((size_t)(i0 + k) * kB + b) * kCV + cv) << 2);
        u[k][0] = ld_carry(cp + 0);
        u[k][1] = ld_carry(cp + 1);
        u[k][2] = ld_carry(cp + 2);
        u[k][3] = ld_carry(cp + 3);
      }
    }
#pragma unroll
    for (int k = 0; k < 4; ++k) {
      if (k < n) {
        const unsigned long long* cp =
            carry + ((((size_t)(i0 + k) * kB + b) * kCV + cv) << 2);
        while (!((u[k][0] >> 32) & (u[k][1] >> 32) & (u[k][2] >> 32) &
                 (u[k][3] >> 32))) {
          __builtin_amdgcn_s_sleep(2);
          u[k][0] = ld_carry(cp + 0);
          u[k][1] = ld_carry(cp + 1);
          u[k][2] = ld_carry(cp + 2);
          u[k][3] = ld_carry(cp + 3);
        }
        union { unsigned uu; float f; } w;
        w.uu = (unsigned)u[k][0]; G0 = fmaf(l32[0], G0, w.f);
        w.uu = (unsigned)u[k][1]; G1 = fmaf(l32[1], G1, w.f);
        w.uu = (unsigned)u[k][2]; G2 = fmaf(l32[2], G2, w.f);
        w.uu = (unsigned)u[k][3]; G3 = fmaf(l32[3], G3, w.f);
        p0 *= l32[0];
        p1 *= l32[1];
        p2 *= l32[2];
        p3 *= l32[3];
      }
    }
  }

  // Seeds. h=0 scans rows 0..15 seeded by G (= S at t=32j-1);
  // h=1 scans rows 16..31 seeded by L + lam^16 * G (= S at t=32j+15).
  // Q from closed form: Q_pre = (1 - lam^t0) / (1 - lam).
  float S0, S1, S2, S3, pq0, pq1, pq2, pq3;
  if (h == 0) {
    S0 = G0; S1 = G1; S2 = G2; S3 = G3;
    pq0 = p0; pq1 = p1; pq2 = p2; pq3 = p3;
  } else {
    S0 = fmaf(l16[0], G0, L0);
    S1 = fmaf(l16[1], G1, L1);
    S2 = fmaf(l16[2], G2, L2);
    S3 = fmaf(l16[3], G3, L3);
    pq0 = p0 * l16[0]; pq1 = p1 * l16[1];
    pq2 = p2 * l16[2]; pq3 = p3 * l16[3];
  }
  float Q0 = (1.0f - pq0) * __builtin_amdgcn_rcpf(1.0f - lam[0]);
  float Q1 = (1.0f - pq1) * __builtin_amdgcn_rcpf(1.0f - lam[1]);
  float Q2 = (1.0f - pq2) * __builtin_amdgcn_rcpf(1.0f - lam[2]);
  float Q3 = (1.0f - pq3) * __builtin_amdgcn_rcpf(1.0f - lam[3]);

  // Scan 16 rows from LDS, write y (plain stores).
  const int r0 = h * 16;
  vfloat4* yp = reinterpret_cast<vfloat4*>(y) + cbase;
#pragma unroll 4
  for (int t = 0; t < 16; ++t) {
    vfloat4 v = lds_x[(r0 + t) * kCV + cv];
    S0 = fmaf(lam[0], S0, v.x);
    S1 = fmaf(lam[1], S1, v.y);
    S2 = fmaf(lam[2], S2, v.z);
    S3 = fmaf(lam[3], S3, v.w);
    Q0 = fmaf(lam[0], Q0, 1.0f);
    Q1 = fmaf(lam[1], Q1, 1.0f);
    Q2 = fmaf(lam[2], Q2, 1.0f);
    Q3 = fmaf(lam[3], Q3, 1.0f);
    vfloat4 o;
    o.x = S0 * __builtin_amdgcn_rcpf(Q0);
    o.y = S1 * __builtin_amdgcn_rcpf(Q1);
    o.z = S2 * __builtin_amdgcn_rcpf(Q2);
    o.w = S3 * __builtin_amdgcn_rcpf(Q3);
    yp[(size_t)(r0 + t) * kCV + cv] = o;
  }
}

// Fallback if workspace is too small: fully sequential over T per (b, 4ch).
extern "C" __global__ __launch_bounds__(256) void ewrls_serial(
    const float* __restrict__ x, const float* __restrict__ zl,
    float* __restrict__ y) {
  int idx = blockIdx.x * 256 + threadIdx.x;   // [0, kB*kCV)
  int cv = idx % kCV;
  int b = idx / kCV;
  float lam[4];
  load_lam(zl, cv * 4, lam);
  float S[4] = {0.f, 0.f, 0.f, 0.f};
  float Q[4] = {0.f, 0.f, 0.f, 0.f};
  const size_t base = (size_t)b * kT * kCV + cv;
  const vfloat4* xp = reinterpret_cast<const vfloat4*>(x) + base;
  vfloat4* yp = reinterpret_cast<vfloat4*>(y) + base;
#pragma unroll 4
  for (int t = 0; t < kT; ++t) {
    vfloat4 v = xp[(size_t)t * kCV];
    S[0] = fmaf(lam[0], S[0], v.x);
    S[1] = fmaf(lam[1], S[1], v.y);
    S[2] = fmaf(lam[2], S[2], v.z);
    S[3] = fmaf(lam[3], S[3], v.w);
    Q[0] = fmaf(lam[0], Q[0], 1.0f);
    Q[1] = fmaf(lam[1], Q[1], 1.0f);
    Q[2] = fmaf(lam[2], Q[2], 1.0f);
    Q[3] = fmaf(lam[3], Q[3], 1.0f);
    vfloat4 o;
    o.x = S[0] * __builtin_amdgcn_rcpf(Q[0]);
    o.y = S[1] * __builtin_amdgcn_rcpf(Q[1]);
    o.z = S[2] * __builtin_amdgcn_rcpf(Q[2]);
    o.w = S[3] * __builtin_amdgcn_rcpf(Q[3]);
    yp[(size_t)t * kCV] = o;
  }
}

extern "C" void kernel_launch(void* const* d_in, const int* in_sizes, int n_in,
                              void* d_out, int out_size, void* d_ws,
                              size_t ws_size, hipStream_t stream) {
  const float* x = (const float*)d_in[0];
  const float* zl = (const float*)d_in[1];
  float* y = (float*)d_out;

  const size_t need = kCarryOffB + kCarryU64 * 8;  // ~8.001 MiB
  if (ws_size >= need) {
    unsigned* ws = (unsigned*)d_ws;
    unsigned long long* cw = reinterpret_cast<unsigned long long*>(
        reinterpret_cast<char*>(d_ws) + kCarryOffB);
    ewrls_init<<<(int)((kCarryU64 + 255) / 256), 256, 0, stream>>>(cw, ws);
    ewrls_fused<<<kChunks, 256, 0, stream>>>(x, zl, ws, y);
  } else {
    const int n = kB * kCV;                 // 8192 -> 32 blocks
    ewrls_serial<<<n / 256, 256, 0, stream>>>(x, zl, y);
  }
}